// Round 3
// baseline (1849.222 us; speedup 1.0000x reference)
//
#include <hip/hip_runtime.h>
#include <math.h>

#define TB 256

__device__ __forceinline__ float fast_sigmoid(float x) {
    return 1.0f / (1.0f + __expf(-x));
}
__device__ __forceinline__ float fast_tanh(float x) {
    float a = fabsf(x);
    float e = __expf(2.0f * a);
    float r = 1.0f - 2.0f / (e + 1.0f);
    return copysignf(r, x);
}
__device__ __forceinline__ float gelu_exact(float x) {
    return 0.5f * x * (1.0f + erff(x * 0.70710678118654752f));
}

// ---------------------------------------------------------------------------
// Kernel A: wave-per-batch recurrent core. 512 blocks x 64 threads (1 wave).
// No inter-wave barriers: __syncthreads in a single-wave workgroup is just an
// lgkmcnt drain. Same algebraic fusion as round 2 (verified):
//   Mkq[d][dp] = sum_e k_w[e][d] q_w[e][dp]
//   MvW[d][e]  = sum_e' v_w[e'][d] wih[e][e']
//   A12[c][col] = sum_d wts[d][c] * (col<32 ? Mkq[d][col] : MvW[d][col-32])
//   c12[col]    = sum_d bts[d]   * (same)
// Per step: feat = gelu(conv(X)); [kq | vWT] = feat@A12 + c12;
//   3x { phaseA: logits(slots,kq)+shfl-softmax -> attn_s, gh in regs;
//        phaseB: gi from attn_s@vWT, GRU combine in regs -> slots_s }
// ---------------------------------------------------------------------------
__global__ __launch_bounds__(64, 1) void slot_recur_wave(
    const float* __restrict__ frames, const float* __restrict__ slot_mu,
    const float* __restrict__ conv_w, const float* __restrict__ conv_b,
    const float* __restrict__ to_slot_w, const float* __restrict__ to_slot_b,
    const float* __restrict__ q_w, const float* __restrict__ k_w,
    const float* __restrict__ v_w,
    const float* __restrict__ wih, const float* __restrict__ whh,
    const float* __restrict__ bih, const float* __restrict__ bhh,
    float* __restrict__ slots_out)
{
    const int l = threadIdx.x;   // 0..63
    const int b = blockIdx.x;

    __shared__ float A12_s[32 * 132];   // [c][col], stride 132
    __shared__ float c12_s[128];
    __shared__ float whh_s[96 * 36];    // [e][d]
    __shared__ float vWT_s[96 * 20];    // [e][n] runtime; wts staging in setup
    __shared__ float kq_s[16 * 36];     // [n][d]
    __shared__ float X_s[16 * 36];      // [n][k], k = half*16 + p*4 + q
    __shared__ float feat_s[16 * 36];   // [n][c]
    __shared__ float slots_s[4 * 36];   // [s][d]
    __shared__ float attn_s[4 * 20];    // [s][n]
    __shared__ float bih_s[96], bhh_s[96];
    __shared__ float Mkq_s[1024];       // setup temp [d][dp]
    __shared__ float scr_s[32 * 96];    // setup temp MvW [d][e]

    // ---- Setup S0: stage raw weights
    for (int i = l; i < 3072; i += 64) A12_s[i] = wih[i];          // wih staged
    for (int i = l; i < 1024; i += 64) {
        whh_s[i]        = v_w[i];
        whh_s[1024 + i] = k_w[i];
        whh_s[2048 + i] = q_w[i];
        vWT_s[i]        = to_slot_w[i];                             // wts staged
    }
    __syncthreads();

    // ---- Setup S1: Mkq, MvW
    for (int o = l; o < 1024; o += 64) {
        int d = o >> 5, dp = o & 31;
        float acc = 0.f;
#pragma unroll 8
        for (int e = 0; e < 32; ++e)
            acc += whh_s[1024 + e * 32 + d] * whh_s[2048 + e * 32 + dp];
        Mkq_s[o] = acc;
    }
    for (int o = l; o < 3072; o += 64) {
        int d = o / 96, e = o - d * 96;
        float acc = 0.f;
#pragma unroll 8
        for (int ep = 0; ep < 32; ++ep)
            acc += whh_s[ep * 32 + d] * A12_s[e * 32 + ep];
        scr_s[d * 96 + e] = acc;
    }
    __syncthreads();

    // ---- Setup S2: A12/c12 (reads wts@vWT_s, Mkq_s, scr_s) + real loads
    for (int o = l; o < 4096; o += 64) {
        int c = o >> 7, col = o & 127;
        float acc = 0.f;
        if (col < 32) {
#pragma unroll 8
            for (int d = 0; d < 32; ++d) acc += vWT_s[d * 32 + c] * Mkq_s[d * 32 + col];
        } else {
            int e = col - 32;
#pragma unroll 8
            for (int d = 0; d < 32; ++d) acc += vWT_s[d * 32 + c] * scr_s[d * 96 + e];
        }
        A12_s[c * 132 + col] = acc;   // overwrites staged wih (consumed in S1)
    }
    for (int col = l; col < 128; col += 64) {
        float acc = 0.f;
        if (col < 32) {
            for (int d = 0; d < 32; ++d) acc += to_slot_b[d] * Mkq_s[d * 32 + col];
        } else {
            int e = col - 32;
            for (int d = 0; d < 32; ++d) acc += to_slot_b[d] * scr_s[d * 96 + e];
        }
        c12_s[col] = acc;
    }
    for (int i = l; i < 3072; i += 64) whh_s[(i >> 5) * 36 + (i & 31)] = whh[i];
    for (int i = l; i < 96; i += 64) { bih_s[i] = bih[i]; bhh_s[i] = bhh[i]; }
    for (int i = l; i < 128; i += 64) slots_s[(i >> 5) * 36 + (i & 31)] = slot_mu[i];

    // conv weight row (time-invariant) -> registers; conv bias scalar
    const int o_c = l & 31, h_c = l >> 5;
    float cw[32];
    {
        const float* wp = conv_w + o_c * 32;
#pragma unroll
        for (int k = 0; k < 32; k += 4) {
            float4 v = *(const float4*)&wp[k];
            cw[k] = v.x; cw[k + 1] = v.y; cw[k + 2] = v.z; cw[k + 3] = v.w;
        }
    }
    const float cb = conv_b[o_c];

    // X(t=0): cur = frame 1, prv = frame 0
    const float* fb = frames + (size_t)b * (128 * 256);
    {
        int i = l >> 2, j4 = l & 3;
        float4 c4 = *(const float4*)&fb[256 + i * 16 + j4 * 4];
        float4 p4 = *(const float4*)&fb[0 + i * 16 + j4 * 4];
        int n = (i >> 2) * 4 + j4, p = i & 3;
        *(float4*)&X_s[n * 36 + p * 4] = c4;
        *(float4*)&X_s[n * 36 + 16 + p * 4] = p4;
    }
    __syncthreads();

    float* so = slots_out + (size_t)b * (126 * 128);
    const int s_id = l >> 4, u = l & 15;
    const int c0 = 2 * l;

#pragma unroll 1
    for (int t = 0; t < 126; ++t) {
        // ---- P1: conv + gelu -> feat[n][o], n = h_c*8 + j
#pragma unroll
        for (int j = 0; j < 8; ++j) {
            int n = h_c * 8 + j;
            const float* xr = &X_s[n * 36];
            float acc = cb;
#pragma unroll
            for (int k = 0; k < 32; k += 4) {
                float4 x4 = *(const float4*)&xr[k];
                acc += cw[k] * x4.x + cw[k + 1] * x4.y + cw[k + 2] * x4.z + cw[k + 3] * x4.w;
            }
            feat_s[n * 36 + o_c] = gelu_exact(acc);
        }
        __syncthreads();

        // prefetch next step's frames into registers
        float4 pfc, pfp;
        if (t < 125) {
            int i = l >> 2, j4 = l & 3;
            pfc = *(const float4*)&fb[(t + 2) * 256 + i * 16 + j4 * 4];
            pfp = *(const float4*)&fb[(t + 1) * 256 + i * 16 + j4 * 4];
        }

        // ---- P2: cols (c0, c0+1) of [kq | vWT] over 16 rows
        float accx[16], accy[16];
#pragma unroll
        for (int n = 0; n < 16; ++n) { accx[n] = 0.f; accy[n] = 0.f; }
#pragma unroll
        for (int cc = 0; cc < 32; cc += 8) {
            float ax[8], ay[8];
#pragma unroll
            for (int c = 0; c < 8; ++c) {
                float2 a = *(const float2*)&A12_s[(cc + c) * 132 + c0];
                ax[c] = a.x; ay[c] = a.y;
            }
#pragma unroll
            for (int n = 0; n < 16; ++n) {
                const float* fr = &feat_s[n * 36 + cc];
                float4 f0 = *(const float4*)&fr[0];
                float4 f1 = *(const float4*)&fr[4];
                accx[n] += f0.x * ax[0] + f0.y * ax[1] + f0.z * ax[2] + f0.w * ax[3]
                         + f1.x * ax[4] + f1.y * ax[5] + f1.z * ax[6] + f1.w * ax[7];
                accy[n] += f0.x * ay[0] + f0.y * ay[1] + f0.z * ay[2] + f0.w * ay[3]
                         + f1.x * ay[4] + f1.y * ay[5] + f1.z * ay[6] + f1.w * ay[7];
            }
        }
        {
            float cx = c12_s[c0], cy = c12_s[c0 + 1];
            if (l < 16) {
#pragma unroll
                for (int n = 0; n < 16; ++n)
                    *(float2*)&kq_s[n * 36 + c0] = make_float2(accx[n] + cx, accy[n] + cy);
            } else {
                int e0 = c0 - 32;
#pragma unroll
                for (int n4 = 0; n4 < 16; n4 += 4) {
                    float4 vx = make_float4(accx[n4] + cx, accx[n4 + 1] + cx,
                                            accx[n4 + 2] + cx, accx[n4 + 3] + cx);
                    float4 vy = make_float4(accy[n4] + cy, accy[n4 + 1] + cy,
                                            accy[n4 + 2] + cy, accy[n4 + 3] + cy);
                    *(float4*)&vWT_s[e0 * 20 + n4] = vx;
                    *(float4*)&vWT_s[(e0 + 1) * 20 + n4] = vy;
                }
            }
        }
        __syncthreads();

        // ---- 3 slot-attention iterations, lane = (s_id, u)
#pragma unroll 1
        for (int it = 0; it < 3; ++it) {
            // Phase A: slots row -> regs; logits + shfl-softmax; gh in regs
            float sr[32];
#pragma unroll
            for (int k = 0; k < 32; k += 4) {
                float4 v = *(const float4*)&slots_s[s_id * 36 + k];
                sr[k] = v.x; sr[k + 1] = v.y; sr[k + 2] = v.z; sr[k + 3] = v.w;
            }
            float h0 = slots_s[s_id * 36 + u];
            float h1 = slots_s[s_id * 36 + u + 16];
            {
                const float* kr = &kq_s[u * 36];
                float lg = 0.f;
#pragma unroll
                for (int k = 0; k < 32; k += 4) {
                    float4 kv = *(const float4*)&kr[k];
                    lg += sr[k] * kv.x + sr[k + 1] * kv.y + sr[k + 2] * kv.z + sr[k + 3] * kv.w;
                }
                lg *= 0.17677669529663687f;   // 1/sqrt(32)
                float m = fmaxf(lg, __shfl_xor(lg, 16));
                m = fmaxf(m, __shfl_xor(m, 32));
                float e = __expf(lg - m);
                float ssum = e + __shfl_xor(e, 16);
                ssum += __shfl_xor(ssum, 32);
                attn_s[s_id * 20 + u] = e / ssum;
            }
            float gh[6];
#pragma unroll
            for (int j = 0; j < 6; ++j) {
                int ee = u + 16 * j;
                const float* wr = &whh_s[ee * 36];
                float acc = bhh_s[ee];
#pragma unroll
                for (int k = 0; k < 32; k += 4) {
                    float4 w4 = *(const float4*)&wr[k];
                    acc += sr[k] * w4.x + sr[k + 1] * w4.y + sr[k + 2] * w4.z + sr[k + 3] * w4.w;
                }
                gh[j] = acc;
            }
            __syncthreads();

            // Phase B: gi from attn row; GRU combine in registers
            float ar[16];
#pragma unroll
            for (int k = 0; k < 16; k += 4) {
                float4 a4 = *(const float4*)&attn_s[s_id * 20 + k];
                ar[k] = a4.x; ar[k + 1] = a4.y; ar[k + 2] = a4.z; ar[k + 3] = a4.w;
            }
            float gi[6];
#pragma unroll
            for (int j = 0; j < 6; ++j) {
                int ee = u + 16 * j;
                const float* vr = &vWT_s[ee * 20];
                float acc = bih_s[ee];
#pragma unroll
                for (int k = 0; k < 16; k += 4) {
                    float4 v4 = *(const float4*)&vr[k];
                    acc += ar[k] * v4.x + ar[k + 1] * v4.y + ar[k + 2] * v4.z + ar[k + 3] * v4.w;
                }
                gi[j] = acc;
            }
            float r0 = fast_sigmoid(gi[0] + gh[0]);
            float r1 = fast_sigmoid(gi[1] + gh[1]);
            float z0 = fast_sigmoid(gi[2] + gh[2]);
            float z1 = fast_sigmoid(gi[3] + gh[3]);
            float n0 = fast_tanh(gi[4] + r0 * gh[4]);
            float n1 = fast_tanh(gi[5] + r1 * gh[5]);
            float hn0 = (1.f - z0) * n0 + z0 * h0;
            float hn1 = (1.f - z1) * n1 + z1 * h1;
            slots_s[s_id * 36 + u] = hn0;
            slots_s[s_id * 36 + u + 16] = hn1;
            if (it == 2) {
                so[t * 128 + s_id * 32 + u] = hn0;
                so[t * 128 + s_id * 32 + u + 16] = hn1;
            }
            __syncthreads();
        }

        // write prefetched frames into X_s for next step
        if (t < 125) {
            int i = l >> 2, j4 = l & 3;
            int n = (i >> 2) * 4 + j4, p = i & 3;
            *(float4*)&X_s[n * 36 + p * 4] = pfc;
            *(float4*)&X_s[n * 36 + 16 + p * 4] = pfp;
        }
        __syncthreads();
    }
}

// ---------------------------------------------------------------------------
// Kernel B: batched decode. GEMM (64512 x 512) = slots_traj (64512 x 128) @
// dec_w^T, fused deconv(4x4,s4) + tanh + add curr + clip. 32 rows per block.
// ---------------------------------------------------------------------------
__global__ __launch_bounds__(TB, 1) void decode_kernel(
    const float* __restrict__ slots_traj, const float* __restrict__ frames,
    const float* __restrict__ dec_w, const float* __restrict__ dec_b,
    const float* __restrict__ deconv_w, const float* __restrict__ deconv_b,
    float* __restrict__ out)
{
    const int tid = threadIdx.x;
    const int m0 = blockIdx.x * 32;

    __shared__ float sl_s[32 * 132];
    __shared__ float wch_s[64 * 132];
    __shared__ float dw_s[512];
    __shared__ float db_s[512];

    for (int i = tid * 4; i < 32 * 128; i += TB * 4) {
        float4 v = *(const float4*)&slots_traj[(size_t)m0 * 128 + i];
        int r = i >> 7, k = i & 127;
        *(float4*)&sl_s[r * 132 + k] = v;
    }
    for (int i = tid; i < 512; i += TB) {
        dw_s[i] = deconv_w[i];
        db_s[i] = dec_b[i];
    }
    __syncthreads();

    const int cg = tid & 63;
    const int rg = tid >> 6;

    float acc[8][8];
#pragma unroll
    for (int ci = 0; ci < 8; ++ci)
#pragma unroll
        for (int rr = 0; rr < 8; ++rr) acc[ci][rr] = 0.f;

    const float* slb = &sl_s[(rg * 8) * 132];

#pragma unroll
    for (int ch = 0; ch < 8; ++ch) {
        for (int i = tid * 4; i < 64 * 128; i += TB * 4) {
            float4 v = *(const float4*)&dec_w[(size_t)ch * 8192 + i];
            int cl = i >> 7, k = i & 127;
            *(float4*)&wch_s[cl * 132 + k] = v;
        }
        __syncthreads();
        const float* wrow = &wch_s[cg * 132];
#pragma unroll 4
        for (int k = 0; k < 128; k += 4) {
            float4 w4 = *(const float4*)&wrow[k];
#pragma unroll
            for (int rr = 0; rr < 8; ++rr) {
                float4 s4 = *(const float4*)&slb[rr * 132 + k];
                acc[ch][rr] += w4.x * s4.x + w4.y * s4.y + w4.z * s4.z + w4.w * s4.w;
            }
        }
        __syncthreads();
    }

#pragma unroll
    for (int ci = 0; ci < 8; ++ci) {
        float bo = db_s[cg + 64 * ci];
#pragma unroll
        for (int rr = 0; rr < 8; ++rr) acc[ci][rr] += bo;
    }

    const int c0 = cg >> 4;
    const int sp = cg & 15;
    const int bi = sp >> 2, bj = sp & 3;
    const float db0 = deconv_b[0];

#pragma unroll 1
    for (int rr = 0; rr < 8; ++rr) {
        float part[16];
#pragma unroll
        for (int kl = 0; kl < 16; ++kl) part[kl] = 0.f;
#pragma unroll
        for (int m = 0; m < 8; ++m) {
            float sf = acc[m][rr];
            const float* dwp = &dw_s[(c0 + 4 * m) * 16];
#pragma unroll
            for (int kl = 0; kl < 16; ++kl) part[kl] += sf * dwp[kl];
        }
#pragma unroll
        for (int kl = 0; kl < 16; ++kl) {
            part[kl] += __shfl_xor(part[kl], 16);
            part[kl] += __shfl_xor(part[kl], 32);
        }
        if (c0 == 0) {
            int mrow = m0 + rg * 8 + rr;
            int bb = mrow / 126, tt = mrow - bb * 126;
            const float* fr = frames + ((size_t)bb * 128 + (tt + 1)) * 256;
            float* op = out + (size_t)mrow * 256;
#pragma unroll
            for (int kk = 0; kk < 4; ++kk) {
                int pixb = (bi * 4 + kk) * 16 + bj * 4;
                float4 c4 = *(const float4*)&fr[pixb];
                float4 o4;
                o4.x = fminf(fmaxf(c4.x + tanhf(part[kk * 4 + 0] + db0), 0.f), 1.f);
                o4.y = fminf(fmaxf(c4.y + tanhf(part[kk * 4 + 1] + db0), 0.f), 1.f);
                o4.z = fminf(fmaxf(c4.z + tanhf(part[kk * 4 + 2] + db0), 0.f), 1.f);
                o4.w = fminf(fmaxf(c4.w + tanhf(part[kk * 4 + 3] + db0), 0.f), 1.f);
                *(float4*)&op[pixb] = o4;
            }
        }
    }
}

extern "C" void kernel_launch(void* const* d_in, const int* in_sizes, int n_in,
                              void* d_out, int out_size, void* d_ws, size_t ws_size,
                              hipStream_t stream) {
    const float* frames    = (const float*)d_in[0];
    const float* slot_mu   = (const float*)d_in[1];
    const float* conv_w    = (const float*)d_in[2];
    const float* conv_b    = (const float*)d_in[3];
    const float* to_slot_w = (const float*)d_in[4];
    const float* to_slot_b = (const float*)d_in[5];
    const float* q_w       = (const float*)d_in[6];
    const float* k_w       = (const float*)d_in[7];
    const float* v_w       = (const float*)d_in[8];
    const float* gru_wih   = (const float*)d_in[9];
    const float* gru_whh   = (const float*)d_in[10];
    const float* gru_bih   = (const float*)d_in[11];
    const float* gru_bhh   = (const float*)d_in[12];
    const float* dec_w     = (const float*)d_in[13];
    const float* dec_b     = (const float*)d_in[14];
    const float* deconv_w  = (const float*)d_in[15];
    const float* deconv_b  = (const float*)d_in[16];

    float* slots_traj = (float*)d_ws;  // 512*126*128 floats = 33 MB
    float* outp = (float*)d_out;

    hipLaunchKernelGGL(slot_recur_wave, dim3(512), dim3(64), 0, stream,
                       frames, slot_mu, conv_w, conv_b, to_slot_w, to_slot_b,
                       q_w, k_w, v_w, gru_wih, gru_whh, gru_bih, gru_bhh,
                       slots_traj);
    hipLaunchKernelGGL(decode_kernel, dim3(64512 / 32), dim3(TB), 0, stream,
                       slots_traj, frames, dec_w, dec_b, deconv_w, deconv_b,
                       outp);
}